// Round 1
// 612.076 us; speedup vs baseline: 1.0028x; 1.0028x over previous
//
#include <hip/hip_runtime.h>
#include <cstdint>
#include <cstddef>

// Problem constants (fixed by reference)
#define BATCH 32
#define SEQ   2048
#define DIM   1024      // ENC_D = DEC_D = ATTN_D = OUT_D = 1024
#define MROWS (BATCH*SEQ)   // 65536

typedef __attribute__((ext_vector_type(4))) float  floatx4;
typedef __attribute__((ext_vector_type(8))) short  short8;

// fp32 -> bf16 round-to-nearest-even
__device__ __forceinline__ unsigned short f2bf(float f) {
  unsigned int u = __float_as_uint(f);
  u += 0x7fffu + ((u >> 16) & 1u);
  return (unsigned short)(u >> 16);
}

// async global->LDS, 16B per lane; LDS dest = wave-uniform base + lane*16
__device__ __forceinline__ void async16(const void* g, void* l) {
  __builtin_amdgcn_global_load_lds(
      (const __attribute__((address_space(1))) unsigned int*)g,
      (__attribute__((address_space(3))) unsigned int*)l, 16, 0, 0);
}

__device__ __forceinline__ float fast_tanh(float x) {
  float e = __expf(2.0f * x);
  return 1.0f - 2.0f * __builtin_amdgcn_rcpf(1.0f + e);
}

// ---------------------------------------------------------------------------
// Kernel 0: Abf[b][s][k] = bf16(enc_states[b][s][k]); rows >= len skipped
// (GEMM tiles covering them read poison, which is a tiny bf16 value; those
//  score rows are masked in softmax, so garbage never propagates.)
// ---------------------------------------------------------------------------
__global__ void k_convert(const float* __restrict__ enc, const int* __restrict__ enc_len,
                          unsigned short* __restrict__ Abf) {
  int b = blockIdx.y;
  int r0 = blockIdx.x * 8;                 // 8 rows per block
  if (r0 >= enc_len[b]) return;
  size_t base = ((size_t)b * SEQ + r0) * DIM;
  const float4* src = (const float4*)(enc + base);
  ushort4* dst = (ushort4*)(Abf + base);
  int tid = threadIdx.x;
#pragma unroll
  for (int i = 0; i < 8; ++i) {
    float4 v = src[tid + i * 256];
    ushort4 h;
    h.x = f2bf(v.x); h.y = f2bf(v.y); h.z = f2bf(v.z); h.w = f2bf(v.w);
    dst[tid + i * 256] = h;
  }
}

// ---------------------------------------------------------------------------
// Kernel 1: Wt[n][k] = bf16(W_enc[k][n])  (1024x1024)
// ---------------------------------------------------------------------------
__global__ void k_transpose(const float* __restrict__ W, unsigned short* __restrict__ Wt) {
  __shared__ float tile[32][33];
  int n0 = blockIdx.x * 32, k0 = blockIdx.y * 32;
  int tx = threadIdx.x, ty = threadIdx.y;   // (32, 8)
#pragma unroll
  for (int i = 0; i < 4; ++i) {
    int y = ty + i * 8;
    tile[y][tx] = W[(size_t)(k0 + y) * DIM + n0 + tx];
  }
  __syncthreads();
#pragma unroll
  for (int i = 0; i < 4; ++i) {
    int y = ty + i * 8;
    Wt[(size_t)(n0 + y) * DIM + k0 + tx] = f2bf(tile[tx][y]);
  }
}

// ---------------------------------------------------------------------------
// Kernel 2: dech[b][a] += dec_states[b, z-chunk] @ W_dec[z-chunk, a]
// split-K x8 (grid.z) for parallelism; chunk 0 adds biases; dech pre-zeroed
// ---------------------------------------------------------------------------
__global__ void k_dech(const float* __restrict__ dec, const float* __restrict__ W_dec,
                       const float* __restrict__ b_dec, const float* __restrict__ b_enc,
                       float* __restrict__ dech) {
  int b = blockIdx.y, z = blockIdx.z;
  int a = blockIdx.x * 256 + threadIdx.x;
  float acc = (z == 0) ? (b_dec[a] + b_enc[a]) : 0.0f;
  const float* dr = dec + (size_t)b * DIM + z * 128;
  const float* wc = W_dec + (size_t)z * 128 * DIM + a;
#pragma unroll 8
  for (int e = 0; e < 128; ++e)
    acc = fmaf(dr[e], wc[(size_t)e * DIM], acc);
  atomicAdd(&dech[(size_t)b * DIM + a], acc);
}

// ---------------------------------------------------------------------------
// Kernel 3 (fast path): m97-structure GEMM + tanh-dot epilogue, bf16 A.
//   score[m] += sum_n tanh( (enc@W_enc)[m][n] + dech[b(m)][n] ) * w_attn[n]
// 128x128 tile, BK=32, 16x16x32 bf16 MFMA, 4 waves (2x2 of 64x64).
// Both operands staged via global_load_lds width=16 into linear 64B-row LDS;
// ds_read_b128 fragment reads from 64B rows are bank-balanced (8/bank).
// ---------------------------------------------------------------------------
__global__ void __launch_bounds__(256, 2) k_gemm_bf16(
    const unsigned short* __restrict__ Abf, // [65536,1024] bf16
    const unsigned short* __restrict__ Wt,  // [1024 n][1024 k] bf16
    const float* __restrict__ dech,         // [32,1024]
    const float* __restrict__ w_attn,       // [1024]
    const int* __restrict__ enc_len,        // [32]
    float* __restrict__ score)              // [65536], pre-zeroed
{
  int linear = blockIdx.x;          // 0..4095
  int xcd = linear & 7;
  int j   = linear >> 3;
  int rb  = xcd * 64 + (j >> 3);    // row block 0..511 (8 col-blocks adjacent per XCD)
  int nb  = j & 7;                  // col block 0..7

  int bb  = rb >> 4;
  int len = enc_len[bb];
  if (((rb & 15) * 128) >= len) return;   // fully masked tile

  __shared__ __align__(16) unsigned short sA[128 * 32];  // 8 KB, 64B per row
  __shared__ __align__(16) unsigned short sB[128 * 32];  // 8 KB, 64B per n-row

  int tid  = threadIdx.x;
  int w    = tid >> 6, lane = tid & 63;
  int wm   = (w >> 1) * 64, wn = (w & 1) * 64;
  int li   = lane & 15, g = lane >> 4;

  const unsigned short* Ab = Abf + (size_t)rb * 128 * DIM;
  const unsigned short* Bb = Wt  + (size_t)nb * 128 * DIM;

  floatx4 acc[4][4] = {};

  for (int kb = 0; kb < 32; ++kb) {
    __syncthreads();
    // stage A and B: chunk p holds row p>>2, k-quarter p&3 (8 bf16 = 16 B)
#pragma unroll
    for (int r = 0; r < 2; ++r) {
      int seg = r * 4 + w;                 // 0..7 (wave-uniform)
      int p   = seg * 64 + lane;           // 0..511
      int row = p >> 2, q = p & 3;
      size_t goff = (size_t)row * DIM + kb * 32 + q * 8;
      async16(Ab + goff, (char*)sA + seg * 1024);
      async16(Bb + goff, (char*)sB + seg * 1024);
    }
    __syncthreads();

    short8 af[4], bfr[4];
#pragma unroll
    for (int t = 0; t < 4; ++t) {
      int row = wm + t * 16 + li;
      af[t]  = *(const short8*)&sA[(row * 4 + g) * 8];
      int n  = wn + t * 16 + li;
      bfr[t] = *(const short8*)&sB[(n * 4 + g) * 8];
    }
#pragma unroll
    for (int tm = 0; tm < 4; ++tm)
#pragma unroll
      for (int tn = 0; tn < 4; ++tn)
        acc[tm][tn] = __builtin_amdgcn_mfma_f32_16x16x32_bf16(af[tm], bfr[tn], acc[tm][tn], 0, 0, 0);
  }

  // epilogue: C/D layout col=lane&15, row=(lane>>4)*4+reg  [m89]
  float dh[4], wa[4];
#pragma unroll
  for (int tn = 0; tn < 4; ++tn) {
    int n = nb * 128 + wn + tn * 16 + li;
    dh[tn] = dech[(size_t)bb * DIM + n];
    wa[tn] = w_attn[n];
  }
#pragma unroll
  for (int tm = 0; tm < 4; ++tm) {
    int mrow = rb * 128 + wm + tm * 16 + g * 4;
#pragma unroll
    for (int r = 0; r < 4; ++r) {
      float v = 0.0f;
#pragma unroll
      for (int tn = 0; tn < 4; ++tn)
        v = fmaf(wa[tn], fast_tanh(acc[tm][tn][r] + dh[tn]), v);
      v += __shfl_xor(v, 1);
      v += __shfl_xor(v, 2);
      v += __shfl_xor(v, 4);
      v += __shfl_xor(v, 8);
      if (li == 0) atomicAdd(&score[mrow + r], v);
    }
  }
}

// ---------------------------------------------------------------------------
// Kernel 3 (fallback, ws too small): previous fp32-staging GEMM (passing)
// ---------------------------------------------------------------------------
__global__ void __launch_bounds__(256, 2) k_gemm_f32(
    const float* __restrict__ A, const unsigned short* __restrict__ Wt,
    const float* __restrict__ dech, const float* __restrict__ w_attn,
    const int* __restrict__ enc_len, float* __restrict__ score)
{
  int linear = blockIdx.x;
  int xcd = linear & 7;
  int j   = linear >> 3;
  int rb  = xcd * 64 + (j >> 3);
  int nb  = j & 7;
  int bb  = rb >> 4;
  int len = enc_len[bb];
  if (((rb & 15) * 128) >= len) return;

  __shared__ __align__(16) unsigned short sA[128 * 40];
  __shared__ __align__(16) unsigned short sB[128 * 32];

  int tid  = threadIdx.x;
  int w    = tid >> 6, lane = tid & 63;
  int wm   = (w >> 1) * 64, wn = (w & 1) * 64;
  int li   = lane & 15, g = lane >> 4;

  const float*          Abase = A  + (size_t)rb * 128 * DIM;
  const unsigned short* Bbase = Wt + (size_t)nb * 128 * DIM;

  floatx4 acc[4][4] = {};

  for (int kb = 0; kb < 32; ++kb) {
    __syncthreads();
#pragma unroll
    for (int i = 0; i < 2; ++i) {
      int c  = (w * 2 + i) * 64 + lane;
      int n  = c >> 2;
      int kh = (c & 3) ^ ((n >> 1) & 3);
      async16(Bbase + (size_t)n * DIM + kb * 32 + kh * 8, (char*)sB + (w * 2 + i) * 1024);
    }
#pragma unroll
    for (int i = 0; i < 4; ++i) {
      int f4  = tid + i * 256;
      int row = f4 >> 3, kq = f4 & 7;
      float4 v = *(const float4*)(Abase + (size_t)row * DIM + kb * 32 + kq * 4);
      ushort4 h;
      h.x = f2bf(v.x); h.y = f2bf(v.y); h.z = f2bf(v.z); h.w = f2bf(v.w);
      *(ushort4*)&sA[row * 40 + kq * 4] = h;
    }
    __syncthreads();

    short8 af[4], bfr[4];
#pragma unroll
    for (int t = 0; t < 4; ++t) {
      int row = wm + t * 16 + li;
      af[t] = *(const short8*)&sA[row * 40 + g * 8];
      int nl = wn + t * 16 + li;
      int phys = (nl << 2) | (g ^ ((nl >> 1) & 3));
      bfr[t] = *(const short8*)((const char*)sB + phys * 16);
    }
#pragma unroll
    for (int tm = 0; tm < 4; ++tm)
#pragma unroll
      for (int tn = 0; tn < 4; ++tn)
        acc[tm][tn] = __builtin_amdgcn_mfma_f32_16x16x32_bf16(af[tm], bfr[tn], acc[tm][tn], 0, 0, 0);
  }

  float dh[4], wa[4];
#pragma unroll
  for (int tn = 0; tn < 4; ++tn) {
    int n = nb * 128 + wn + tn * 16 + li;
    dh[tn] = dech[(size_t)bb * DIM + n];
    wa[tn] = w_attn[n];
  }
#pragma unroll
  for (int tm = 0; tm < 4; ++tm) {
    int mrow = rb * 128 + wm + tm * 16 + g * 4;
#pragma unroll
    for (int r = 0; r < 4; ++r) {
      float v = 0.0f;
#pragma unroll
      for (int tn = 0; tn < 4; ++tn)
        v = fmaf(wa[tn], fast_tanh(acc[tm][tn][r] + dh[tn]), v);
      v += __shfl_xor(v, 1);
      v += __shfl_xor(v, 2);
      v += __shfl_xor(v, 4);
      v += __shfl_xor(v, 8);
      if (li == 0) atomicAdd(&score[mrow + r], v);
    }
  }
}

// ---------------------------------------------------------------------------
// Kernel 4: masked softmax per batch row. SCALING == 1.0 (folded out).
// ---------------------------------------------------------------------------
__global__ void k_softmax(const float* __restrict__ score, const int* __restrict__ enc_len,
                          float* __restrict__ attn) {
  int b = blockIdx.x, tid = threadIdx.x;
  int len = enc_len[b];
  __shared__ float red[256];
  float v[8];
  float m = -1e30f;
#pragma unroll
  for (int i = 0; i < 8; ++i) {
    int s = tid + i * 256;
    v[i] = score[(size_t)b * SEQ + s];
    if (s < len) m = fmaxf(m, v[i]);
  }
  red[tid] = m; __syncthreads();
  for (int st = 128; st > 0; st >>= 1) {
    if (tid < st) red[tid] = fmaxf(red[tid], red[tid + st]);
    __syncthreads();
  }
  float mx = red[0]; __syncthreads();
  float sum = 0.0f;
#pragma unroll
  for (int i = 0; i < 8; ++i) {
    int s = tid + i * 256;
    float e = (s < len) ? __expf(v[i] - mx) : 0.0f;
    v[i] = e; sum += e;
  }
  red[tid] = sum; __syncthreads();
  for (int st = 128; st > 0; st >>= 1) {
    if (tid < st) red[tid] += red[tid + st];
    __syncthreads();
  }
  float inv = 1.0f / red[0];
#pragma unroll
  for (int i = 0; i < 8; ++i)
    attn[(size_t)b * SEQ + tid + i * 256] = v[i] * inv;
}

// ---------------------------------------------------------------------------
// Kernel 5: ctx[b][e] += sum_s attn[b][s] * enc[b][s][e]   (memory-bound)
// ROUND 1 REWRITE: was latency-bound (~1 outstanding 16B load/wave, runtime
// trip count blocked unrolling -> ~0.6-1 TB/s). Now: 32-row chunks (2048
// blocks, 8/CU, 32 waves/CU) + manual 8x unroll = 8 independent float4 +
// 8 broadcast loads in flight per wave. len >= 1024 so chunks 0..31 are
// always full (unrolled path); only tail chunks hit the remainder loop.
// ---------------------------------------------------------------------------
__global__ void k_context(const float* __restrict__ enc, const float* __restrict__ attn,
                          const int* __restrict__ enc_len, float* __restrict__ ctx) {
  int b = blockIdx.y, sc = blockIdx.x;   // 64 chunks of 32 rows
  int len = enc_len[b];
  int s0 = sc * 32;
  if (s0 >= len) return;
  int cnt = min(32, len - s0);
  int tid = threadIdx.x;
  const float* base = enc + ((size_t)b * SEQ + s0) * DIM + tid * 4;
  const float* ap   = attn + (size_t)b * SEQ + s0;
  float a0 = 0.f, a1 = 0.f, a2 = 0.f, a3 = 0.f;
  int i = 0;
  for (; i + 8 <= cnt; i += 8) {
    float4 x[8];
    float  w[8];
#pragma unroll
    for (int u = 0; u < 8; ++u)
      x[u] = *(const float4*)(base + (size_t)(i + u) * DIM);
#pragma unroll
    for (int u = 0; u < 8; ++u)
      w[u] = ap[i + u];
#pragma unroll
    for (int u = 0; u < 8; ++u) {
      a0 = fmaf(w[u], x[u].x, a0); a1 = fmaf(w[u], x[u].y, a1);
      a2 = fmaf(w[u], x[u].z, a2); a3 = fmaf(w[u], x[u].w, a3);
    }
  }
  for (; i < cnt; ++i) {
    float w = ap[i];
    float4 x = *(const float4*)(base + (size_t)i * DIM);
    a0 = fmaf(w, x.x, a0); a1 = fmaf(w, x.y, a1);
    a2 = fmaf(w, x.z, a2); a3 = fmaf(w, x.w, a3);
  }
  float* c = ctx + (size_t)b * DIM + tid * 4;
  atomicAdd(c + 0, a0); atomicAdd(c + 1, a1);
  atomicAdd(c + 2, a2); atomicAdd(c + 3, a3);
}

// ---------------------------------------------------------------------------
// Kernel 6: out[b][o] += ctx[b, z-chunk] @ W_out[z-chunk, o]  (split-K x8)
// chunk 0 adds b_out; out pre-zeroed via memset
// ---------------------------------------------------------------------------
__global__ void k_out(const float* __restrict__ ctx, const float* __restrict__ W_out,
                      const float* __restrict__ b_out, float* __restrict__ out) {
  int b = blockIdx.y, z = blockIdx.z;
  int o = blockIdx.x * 256 + threadIdx.x;
  float acc = (z == 0) ? b_out[o] : 0.0f;
  const float* cr = ctx + (size_t)b * DIM + z * 128;
  const float* wc = W_out + (size_t)z * 128 * DIM + o;
#pragma unroll 8
  for (int e = 0; e < 128; ++e)
    acc = fmaf(cr[e], wc[(size_t)e * DIM], acc);
  atomicAdd(&out[(size_t)b * DIM + o], acc);
}

// ---------------------------------------------------------------------------
extern "C" void kernel_launch(void* const* d_in, const int* in_sizes, int n_in,
                              void* d_out, int out_size, void* d_ws, size_t ws_size,
                              hipStream_t stream) {
  (void)in_sizes; (void)n_in; (void)out_size;
  const float* enc_states = (const float*)d_in[0];   // [32,2048,1024]
  const float* dec_states = (const float*)d_in[1];   // [32,1024]
  const float* W_enc      = (const float*)d_in[2];   // [1024,1024]
  const float* b_enc      = (const float*)d_in[3];   // [1024]
  const float* W_dec      = (const float*)d_in[4];   // [1024,1024]
  const float* b_dec      = (const float*)d_in[5];   // [1024]
  const float* w_attn     = (const float*)d_in[6];   // [1024]
  const float* W_out      = (const float*)d_in[7];   // [1024,1024]
  const float* b_out      = (const float*)d_in[8];   // [1024]
  const int*   enc_len    = (const int*)  d_in[9];   // [32]

  float* out_ctx  = (float*)d_out;                   // [32,1024]
  float* out_attn = (float*)d_out + BATCH * DIM;     // [32,2048]

  // workspace layout:
  //   Wt    @ 0        : 2 MB   (bf16 W_enc^T)
  //   score @ 2 MB     : 256 KB (zeroed)
  //   ctx   @ 2.25 MB  : 128 KB (zeroed)
  //   dech  @ 2.375 MB : 128 KB (zeroed)
  //   Abf   @ 3 MB     : 128 MB (bf16 enc_states) -- fast path only
  char* ws = (char*)d_ws;
  unsigned short* Wt  = (unsigned short*)ws;
  float* score = (float*)(ws + (2u << 20));
  float* ctx   = (float*)(ws + (2u << 20) + 262144);
  float* dech  = (float*)(ws + (2u << 20) + 262144 + 131072);
  unsigned short* Abf = (unsigned short*)(ws + (3u << 20));
  const bool fast = ws_size >= ((size_t)(3u << 20) + ((size_t)MROWS * DIM * 2));

  // zero score + ctx + dech (all atomically accumulated)
  hipMemsetAsync(ws + (2u << 20), 0, 262144 + 131072 + 131072, stream);
  // zero out_ctx (atomically accumulated by k_out)
  hipMemsetAsync(d_out, 0, (size_t)BATCH * DIM * sizeof(float), stream);

  k_transpose<<<dim3(32, 32), dim3(32, 8), 0, stream>>>(W_enc, Wt);
  k_dech<<<dim3(4, BATCH, 8), 256, 0, stream>>>(dec_states, W_dec, b_dec, b_enc, dech);
  if (fast) {
    k_convert<<<dim3(SEQ / 8, BATCH), 256, 0, stream>>>(enc_states, enc_len, Abf);
    k_gemm_bf16<<<4096, 256, 0, stream>>>(Abf, Wt, dech, w_attn, enc_len, score);
  } else {
    k_gemm_f32<<<4096, 256, 0, stream>>>(enc_states, Wt, dech, w_attn, enc_len, score);
  }
  k_softmax<<<BATCH, 256, 0, stream>>>(score, enc_len, out_attn);
  k_context<<<dim3(64, BATCH), 256, 0, stream>>>(enc_states, out_attn, enc_len, ctx);
  k_out<<<dim3(4, BATCH, 8), 256, 0, stream>>>(ctx, W_out, b_out, out_ctx);
}

// Round 3
// 601.481 us; speedup vs baseline: 1.0205x; 1.0176x over previous
//
#include <hip/hip_runtime.h>
#include <cstdint>
#include <cstddef>

// Problem constants (fixed by reference)
#define BATCH 32
#define SEQ   2048
#define DIM   1024      // ENC_D = DEC_D = ATTN_D = OUT_D = 1024
#define MROWS (BATCH*SEQ)   // 65536

typedef __attribute__((ext_vector_type(4))) float  floatx4;
typedef __attribute__((ext_vector_type(8))) short  short8;

// fp32 -> bf16 round-to-nearest-even
__device__ __forceinline__ unsigned short f2bf(float f) {
  unsigned int u = __float_as_uint(f);
  u += 0x7fffu + ((u >> 16) & 1u);
  return (unsigned short)(u >> 16);
}

// async global->LDS, 16B per lane; LDS dest = wave-uniform base + lane*16
__device__ __forceinline__ void async16(const void* g, void* l) {
  __builtin_amdgcn_global_load_lds(
      (const __attribute__((address_space(1))) unsigned int*)g,
      (__attribute__((address_space(3))) unsigned int*)l, 16, 0, 0);
}

__device__ __forceinline__ float fast_tanh(float x) {
  float e = __expf(2.0f * x);
  return 1.0f - 2.0f * __builtin_amdgcn_rcpf(1.0f + e);
}

// ---------------------------------------------------------------------------
// Kernel 0: Abf[b][s][k] = bf16(enc_states[b][s][k]); rows >= len skipped
// ---------------------------------------------------------------------------
__global__ void k_convert(const float* __restrict__ enc, const int* __restrict__ enc_len,
                          unsigned short* __restrict__ Abf) {
  int b = blockIdx.y;
  int r0 = blockIdx.x * 8;                 // 8 rows per block
  if (r0 >= enc_len[b]) return;
  size_t base = ((size_t)b * SEQ + r0) * DIM;
  const float4* src = (const float4*)(enc + base);
  ushort4* dst = (ushort4*)(Abf + base);
  int tid = threadIdx.x;
#pragma unroll
  for (int i = 0; i < 8; ++i) {
    float4 v = src[tid + i * 256];
    ushort4 h;
    h.x = f2bf(v.x); h.y = f2bf(v.y); h.z = f2bf(v.z); h.w = f2bf(v.w);
    dst[tid + i * 256] = h;
  }
}

// ---------------------------------------------------------------------------
// Kernel 1: Wt[n][k] = bf16(W_enc[k][n])  (1024x1024)
// ---------------------------------------------------------------------------
__global__ void k_transpose(const float* __restrict__ W, unsigned short* __restrict__ Wt) {
  __shared__ float tile[32][33];
  int n0 = blockIdx.x * 32, k0 = blockIdx.y * 32;
  int tx = threadIdx.x, ty = threadIdx.y;   // (32, 8)
#pragma unroll
  for (int i = 0; i < 4; ++i) {
    int y = ty + i * 8;
    tile[y][tx] = W[(size_t)(k0 + y) * DIM + n0 + tx];
  }
  __syncthreads();
#pragma unroll
  for (int i = 0; i < 4; ++i) {
    int y = ty + i * 8;
    Wt[(size_t)(n0 + y) * DIM + k0 + tx] = f2bf(tile[tx][y]);
  }
}

// ---------------------------------------------------------------------------
// Kernel 2: dech[b][a] += dec_states[b, z-chunk] @ W_dec[z-chunk, a]
// ---------------------------------------------------------------------------
__global__ void k_dech(const float* __restrict__ dec, const float* __restrict__ W_dec,
                       const float* __restrict__ b_dec, const float* __restrict__ b_enc,
                       float* __restrict__ dech) {
  int b = blockIdx.y, z = blockIdx.z;
  int a = blockIdx.x * 256 + threadIdx.x;
  float acc = (z == 0) ? (b_dec[a] + b_enc[a]) : 0.0f;
  const float* dr = dec + (size_t)b * DIM + z * 128;
  const float* wc = W_dec + (size_t)z * 128 * DIM + a;
#pragma unroll 8
  for (int e = 0; e < 128; ++e)
    acc = fmaf(dr[e], wc[(size_t)e * DIM], acc);
  atomicAdd(&dech[(size_t)b * DIM + a], acc);
}

// ---------------------------------------------------------------------------
// Kernel 3: 256x256-tile 8-phase GEMM (T2+T3+T4+T5 port) + tanh-dot epilogue.
//   score[m] += sum_n tanh( (Abf@Wt^T)[m][n] + dech[b(m)][n] ) * w_attn[n]
// BM=BN=256, BK=64, 512 thr = 8 waves (2M x 4N), per-wave 128x64 out.
// LDS 128 KB: A bufs @ 0/32K, B bufs @ 64K/96K; 128 B per row (64 bf16).
// Swizzle: physical = logical ^ (((logical>>7)&7)<<4)  (involution, 16B-granular)
//   read side XORs the k-slot byte; stage side pre-swizzles the per-lane
//   GLOBAL source; LDS dest stays linear (rule 21: both-sides).
//
// R2 RACE FIX: READ_B(·,0) touches stage-half h1 for wc>=2 waves already in
// ph1 (B rows = wc*64+...), so B:h1 must be retired at the PREVIOUS tile's
// ph4-end, not this tile's ph1-end. Wait schedule (per-wave load units,
// issue order per tile t: ph1 At+1:h1, ph2 Bt+1:h0, ph3 Bt+1:h1, ph4 At+2:h0):
//   - prologue VMCNT(2): retires A0 full + B0 full; leaves A1:h0 in flight
//   - MODE0 ph4-end VMCNT(2): retires through Bt+1:h1; leaves At+2:h0
//   - MODE1 ph4-end VMCNT(0) (tail); MODE2 no waits
// No ph1-end VMCNT. Never drains to 0 in steady state. All stage-overwrite
// hazards sit >=1 barrier after their last reader (verified per half).
// ---------------------------------------------------------------------------
#define PH_BAR do { asm volatile("" ::: "memory"); __builtin_amdgcn_s_barrier(); asm volatile("" ::: "memory"); } while(0)
#define SCHED0 __builtin_amdgcn_sched_barrier(0)
#define SP1 __builtin_amdgcn_s_setprio(1)
#define SP0 __builtin_amdgcn_s_setprio(0)
#define VMCNT(n) asm volatile("s_waitcnt vmcnt(" #n ")" ::: "memory")

__global__ void __launch_bounds__(512, 2) k_gemm256(
    const unsigned short* __restrict__ Abf, // [65536,1024] bf16
    const unsigned short* __restrict__ Wt,  // [1024 n][1024 k] bf16
    const float* __restrict__ dech,         // [32,1024]
    const float* __restrict__ w_attn,       // [1024]
    const int* __restrict__ enc_len,        // [32]
    float* __restrict__ score)              // [65536], pre-zeroed
{
  int bid = blockIdx.x;                 // 1024 blocks
  int t  = (bid & 7) * 128 + (bid >> 3); // bijective XCD swizzle (1024%8==0)
  int nb = t & 3;                        // col tile 0..3   (n0 = nb*256)
  int rt = t >> 2;                       // row tile 0..255 (m0 = rt*256)
  int bb = rt >> 3;                      // batch (8 row-tiles per batch)
  int len = enc_len[bb];
  if (((rt & 7) * 256) >= len) return;   // fully masked tile

  __shared__ __align__(16) char lds[131072];

  int tid = threadIdx.x;
  int w = tid >> 6, lane = tid & 63;
  int wr = w >> 2;               // 0..1  M-warp
  int wc = w & 3;                // 0..3  N-warp
  int li = lane & 15, g = lane >> 4;
  int xl = (li & 7) << 4;        // lane-constant read swizzle

  const char* Ag = (const char*)(Abf + (size_t)rt * 256 * DIM);
  const char* Bg = (const char*)(Wt  + (size_t)nb * 256 * DIM);

  // per-lane pre-swizzled stage source offsets (identical geometry for A/B)
  size_t soff[2][2];
  int    ldso[2][2];
#pragma unroll
  for (int h = 0; h < 2; ++h)
#pragma unroll
    for (int i = 0; i < 2; ++i) {
      int P = h * 16384 + (w * 2 + i) * 1024 + lane * 16;  // physical (linear dest)
      int L = P ^ (((P >> 7) & 7) << 4);                   // logical (row,k)
      soff[h][i] = (size_t)(L >> 7) * (DIM * 2) + (L & 127);
      ldso[h][i] = h * 16384 + (w * 2 + i) * 1024;         // wave-uniform dest
    }

#define STAGE_A(buf, h, kt) do { \
  async16(Ag + soff[h][0] + (size_t)(kt) * 128, lds + (buf) * 32768 + ldso[h][0]); \
  async16(Ag + soff[h][1] + (size_t)(kt) * 128, lds + (buf) * 32768 + ldso[h][1]); \
} while (0)
#define STAGE_B(buf, h, kt) do { \
  async16(Bg + soff[h][0] + (size_t)(kt) * 128, lds + 65536 + (buf) * 32768 + ldso[h][0]); \
  async16(Bg + soff[h][1] + (size_t)(kt) * 128, lds + 65536 + (buf) * 32768 + ldso[h][1]); \
} while (0)

  short8 aF[4][2];        // current mh sub: 4 m-frags x 2 ksub
  short8 bF[2][2][2];     // [nh][tnq][ksub], both nh halves stay live
  floatx4 acc[8][4] = {}; // 8 m-frags x 4 n-frags

#define READ_A(buf, mh) do { \
  const char* base_ = lds + (buf) * 32768 + (wr * 128 + (mh) * 64 + li) * 128; \
  int c0_ = (g * 16) ^ xl; \
  _Pragma("unroll") for (int tmq = 0; tmq < 4; ++tmq) { \
    aF[tmq][0] = *(const short8*)(base_ + tmq * 2048 + c0_); \
    aF[tmq][1] = *(const short8*)(base_ + tmq * 2048 + (c0_ ^ 64)); \
  } \
} while (0)
#define READ_B(buf, nh) do { \
  const char* base_ = lds + 65536 + (buf) * 32768 + (wc * 64 + (nh) * 32 + li) * 128; \
  int c0_ = (g * 16) ^ xl; \
  _Pragma("unroll") for (int tnq = 0; tnq < 2; ++tnq) { \
    bF[nh][tnq][0] = *(const short8*)(base_ + tnq * 2048 + c0_); \
    bF[nh][tnq][1] = *(const short8*)(base_ + tnq * 2048 + (c0_ ^ 64)); \
  } \
} while (0)
#define MFMA_Q(mh, nh) do { \
  _Pragma("unroll") for (int ks = 0; ks < 2; ++ks) \
  _Pragma("unroll") for (int tmq = 0; tmq < 4; ++tmq) \
  _Pragma("unroll") for (int tnq = 0; tnq < 2; ++tnq) \
    acc[(mh) * 4 + tmq][(nh) * 2 + tnq] = __builtin_amdgcn_mfma_f32_16x16x32_bf16( \
        aF[tmq][ks], bF[nh][tnq][ks], acc[(mh) * 4 + tmq][(nh) * 2 + tnq], 0, 0, 0); \
} while (0)

// MODE 0: uniform. MODE 1: tile NT-2 (no next2 issue, vmcnt(0) at ph4-end).
// MODE 2: last tile (no issues, no waits).
#define TILE_STEP(CUR, KTN, KTN2, MODE) do { \
  /* ph1: Q(0,0) -- reads A both halves (wr-split) + B rows wc*64..+31 */ \
  READ_A(CUR, 0); \
  READ_B(CUR, 0); \
  if ((MODE) < 2) STAGE_A((CUR) ^ 1, 1, KTN); \
  PH_BAR; SCHED0; SP1; MFMA_Q(0, 0); SP0; SCHED0; \
  PH_BAR; \
  /* ph2: Q(0,1) */ \
  READ_B(CUR, 1); \
  if ((MODE) < 2) STAGE_B((CUR) ^ 1, 0, KTN); \
  PH_BAR; SCHED0; SP1; MFMA_Q(0, 1); SP0; SCHED0; \
  PH_BAR; \
  /* ph3: Q(1,1) */ \
  READ_A(CUR, 1); \
  if ((MODE) < 2) STAGE_B((CUR) ^ 1, 1, KTN); \
  PH_BAR; SCHED0; SP1; MFMA_Q(1, 1); SP0; SCHED0; \
  PH_BAR; \
  /* ph4: Q(1,0) -- operands in regs; A[CUR]:h0 LDS dead after ph3 */ \
  if ((MODE) == 0) STAGE_A(CUR, 0, KTN2); \
  PH_BAR; SCHED0; SP1; MFMA_Q(1, 0); SP0; SCHED0; \
  if ((MODE) == 0) { VMCNT(2); } else if ((MODE) == 1) { VMCNT(0); } \
  PH_BAR; \
} while (0)

  // prologue: t0 full + t1.A0; retire everything except A1:h0
  STAGE_A(0, 0, 0); STAGE_A(0, 1, 0); STAGE_B(0, 0, 0); STAGE_B(0, 1, 0);
  STAGE_A(1, 0, 1);
  VMCNT(2);
  PH_BAR;

  // main: tiles 0..13 (NT=16)
#pragma unroll 1
  for (int u = 0; u < 14; u += 2) {
    TILE_STEP(0, u + 1, u + 2, 0);
    TILE_STEP(1, u + 2, u + 3, 0);
  }
  TILE_STEP(0, 15, 0, 1);   // tile 14
  TILE_STEP(1, 0, 0, 2);    // tile 15

  // epilogue: C/D layout col=lane&15 (n), row=(lane>>4)*4+reg (m)  [m89]
  float dh[4], wa[4];
#pragma unroll
  for (int tn = 0; tn < 4; ++tn) {
    int n = nb * 256 + wc * 64 + tn * 16 + li;
    dh[tn] = dech[(size_t)bb * DIM + n];
    wa[tn] = w_attn[n];
  }
#pragma unroll
  for (int tm = 0; tm < 8; ++tm) {
    int mrow = rt * 256 + wr * 128 + tm * 16 + g * 4;
#pragma unroll
    for (int r = 0; r < 4; ++r) {
      float v = 0.0f;
#pragma unroll
      for (int tn = 0; tn < 4; ++tn)
        v = fmaf(wa[tn], fast_tanh(acc[tm][tn][r] + dh[tn]), v);
      v += __shfl_xor(v, 1);
      v += __shfl_xor(v, 2);
      v += __shfl_xor(v, 4);
      v += __shfl_xor(v, 8);
      if (li == 0) atomicAdd(&score[mrow + r], v);
    }
  }
#undef TILE_STEP
#undef MFMA_Q
#undef READ_B
#undef READ_A
#undef STAGE_B
#undef STAGE_A
}

// ---------------------------------------------------------------------------
// Kernel 3 (fallback, ws too small): fp32-staging GEMM (passing)
// ---------------------------------------------------------------------------
__global__ void __launch_bounds__(256, 2) k_gemm_f32(
    const float* __restrict__ A, const unsigned short* __restrict__ Wt,
    const float* __restrict__ dech, const float* __restrict__ w_attn,
    const int* __restrict__ enc_len, float* __restrict__ score)
{
  int linear = blockIdx.x;
  int xcd = linear & 7;
  int j   = linear >> 3;
  int rb  = xcd * 64 + (j >> 3);
  int nb  = j & 7;
  int bb  = rb >> 4;
  int len = enc_len[bb];
  if (((rb & 15) * 128) >= len) return;

  __shared__ __align__(16) unsigned short sA[128 * 40];
  __shared__ __align__(16) unsigned short sB[128 * 32];

  int tid  = threadIdx.x;
  int w    = tid >> 6, lane = tid & 63;
  int wm   = (w >> 1) * 64, wn = (w & 1) * 64;
  int li   = lane & 15, g = lane >> 4;

  const float*          Abase = A  + (size_t)rb * 128 * DIM;
  const unsigned short* Bbase = Wt + (size_t)nb * 128 * DIM;

  floatx4 acc[4][4] = {};

  for (int kb = 0; kb < 32; ++kb) {
    __syncthreads();
#pragma unroll
    for (int i = 0; i < 2; ++i) {
      int c  = (w * 2 + i) * 64 + lane;
      int n  = c >> 2;
      int kh = (c & 3) ^ ((n >> 1) & 3);
      async16(Bbase + (size_t)n * DIM + kb * 32 + kh * 8, (char*)sB + (w * 2 + i) * 1024);
    }
#pragma unroll
    for (int i = 0; i < 4; ++i) {
      int f4  = tid + i * 256;
      int row = f4 >> 3, kq = f4 & 7;
      float4 v = *(const float4*)(Abase + (size_t)row * DIM + kb * 32 + kq * 4);
      ushort4 h;
      h.x = f2bf(v.x); h.y = f2bf(v.y); h.z = f2bf(v.z); h.w = f2bf(v.w);
      *(ushort4*)&sA[row * 40 + kq * 4] = h;
    }
    __syncthreads();

    short8 af[4], bfr[4];
#pragma unroll
    for (int t = 0; t < 4; ++t) {
      int row = wm + t * 16 + li;
      af[t] = *(const short8*)&sA[row * 40 + g * 8];
      int nl = wn + t * 16 + li;
      int phys = (nl << 2) | (g ^ ((nl >> 1) & 3));
      bfr[t] = *(const short8*)((const char*)sB + phys * 16);
    }
#pragma unroll
    for (int tm = 0; tm < 4; ++tm)
#pragma unroll
      for (int tn = 0; tn < 4; ++tn)
        acc[tm][tn] = __builtin_amdgcn_mfma_f32_16x16x32_bf16(af[tm], bfr[tn], acc[tm][tn], 0, 0, 0);
  }

  float dh[4], wa[4];
#pragma unroll
  for (int tn = 0; tn < 4; ++tn) {
    int n = nb * 128 + wn + tn * 16 + li;
    dh[tn] = dech[(size_t)bb * DIM + n];
    wa[tn] = w_attn[n];
  }
#pragma unroll
  for (int tm = 0; tm < 4; ++tm) {
    int mrow = rb * 128 + wm + tm * 16 + g * 4;
#pragma unroll
    for (int r = 0; r < 4; ++r) {
      float v = 0.0f;
#pragma unroll
      for (int tn = 0; tn < 4; ++tn)
        v = fmaf(wa[tn], fast_tanh(acc[tm][tn][r] + dh[tn]), v);
      v += __shfl_xor(v, 1);
      v += __shfl_xor(v, 2);
      v += __shfl_xor(v, 4);
      v += __shfl_xor(v, 8);
      if (li == 0) atomicAdd(&score[mrow + r], v);
    }
  }
}

// ---------------------------------------------------------------------------
// Kernel 4: masked softmax per batch row. SCALING == 1.0 (folded out).
// ---------------------------------------------------------------------------
__global__ void k_softmax(const float* __restrict__ score, const int* __restrict__ enc_len,
                          float* __restrict__ attn) {
  int b = blockIdx.x, tid = threadIdx.x;
  int len = enc_len[b];
  __shared__ float red[256];
  float v[8];
  float m = -1e30f;
#pragma unroll
  for (int i = 0; i < 8; ++i) {
    int s = tid + i * 256;
    v[i] = score[(size_t)b * SEQ + s];
    if (s < len) m = fmaxf(m, v[i]);
  }
  red[tid] = m; __syncthreads();
  for (int st = 128; st > 0; st >>= 1) {
    if (tid < st) red[tid] = fmaxf(red[tid], red[tid + st]);
    __syncthreads();
  }
  float mx = red[0]; __syncthreads();
  float sum = 0.0f;
#pragma unroll
  for (int i = 0; i < 8; ++i) {
    int s = tid + i * 256;
    float e = (s < len) ? __expf(v[i] - mx) : 0.0f;
    v[i] = e; sum += e;
  }
  red[tid] = sum; __syncthreads();
  for (int st = 128; st > 0; st >>= 1) {
    if (tid < st) red[tid] += red[tid + st];
    __syncthreads();
  }
  float inv = 1.0f / red[0];
#pragma unroll
  for (int i = 0; i < 8; ++i)
    attn[(size_t)b * SEQ + tid + i * 256] = v[i] * inv;
}

// ---------------------------------------------------------------------------
// Kernel 5: ctx[b][e] += sum_s attn[b][s] * enc[b][s][e]   (memory-bound)
// 32-row chunks, manual 8x unroll (8 float4 + 8 scalar loads in flight).
// ---------------------------------------------------------------------------
__global__ void k_context(const float* __restrict__ enc, const float* __restrict__ attn,
                          const int* __restrict__ enc_len, float* __restrict__ ctx) {
  int b = blockIdx.y, sc = blockIdx.x;   // 64 chunks of 32 rows
  int len = enc_len[b];
  int s0 = sc * 32;
  if (s0 >= len) return;
  int cnt = min(32, len - s0);
  int tid = threadIdx.x;
  const float* base = enc + ((size_t)b * SEQ + s0) * DIM + tid * 4;
  const float* ap   = attn + (size_t)b * SEQ + s0;
  float a0 = 0.f, a1 = 0.f, a2 = 0.f, a3 = 0.f;
  int i = 0;
  for (; i + 8 <= cnt; i += 8) {
    float4 x[8];
    float  w[8];
#pragma unroll
    for (int u = 0; u < 8; ++u)
      x[u] = *(const float4*)(base + (size_t)(i + u) * DIM);
#pragma unroll
    for (int u = 0; u < 8; ++u)
      w[u] = ap[i + u];
#pragma unroll
    for (int u = 0; u < 8; ++u) {
      a0 = fmaf(w[u], x[u].x, a0); a1 = fmaf(w[u], x[u].y, a1);
      a2 = fmaf(w[u], x[u].z, a2); a3 = fmaf(w[u], x[u].w, a3);
    }
  }
  for (; i < cnt; ++i) {
    float w = ap[i];
    float4 x = *(const float4*)(base + (size_t)i * DIM);
    a0 = fmaf(w, x.x, a0); a1 = fmaf(w, x.y, a1);
    a2 = fmaf(w, x.z, a2); a3 = fmaf(w, x.w, a3);
  }
  float* c = ctx + (size_t)b * DIM + tid * 4;
  atomicAdd(c + 0, a0); atomicAdd(c + 1, a1);
  atomicAdd(c + 2, a2); atomicAdd(c + 3, a3);
}

// ---------------------------------------------------------------------------
// Kernel 6: out[b][o] += ctx[b, z-chunk] @ W_out[z-chunk, o]  (split-K x8)
// ---------------------------------------------------------------------------
__global__ void k_out(const float* __restrict__ ctx, const float* __restrict__ W_out,
                      const float* __restrict__ b_out, float* __restrict__ out) {
  int b = blockIdx.y, z = blockIdx.z;
  int o = blockIdx.x * 256 + threadIdx.x;
  float acc = (z == 0) ? b_out[o] : 0.0f;
  const float* cr = ctx + (size_t)b * DIM + z * 128;
  const float* wc = W_out + (size_t)z * 128 * DIM + o;
#pragma unroll 8
  for (int e = 0; e < 128; ++e)
    acc = fmaf(cr[e], wc[(size_t)e * DIM], acc);
  atomicAdd(&out[(size_t)b * DIM + o], acc);
}

// ---------------------------------------------------------------------------
extern "C" void kernel_launch(void* const* d_in, const int* in_sizes, int n_in,
                              void* d_out, int out_size, void* d_ws, size_t ws_size,
                              hipStream_t stream) {
  (void)in_sizes; (void)n_in; (void)out_size;
  const float* enc_states = (const float*)d_in[0];   // [32,2048,1024]
  const float* dec_states = (const float*)d_in[1];   // [32,1024]
  const float* W_enc      = (const float*)d_in[2];   // [1024,1024]
  const float* b_enc      = (const float*)d_in[3];   // [1024]
  const float* W_dec      = (const float*)d_in[4];   // [1024,1024]
  const float* b_dec      = (const float*)d_in[5];   // [1024]
  const float* w_attn     = (const float*)d_in[6];   // [1024]
  const float* W_out      = (const float*)d_in[7];   // [1024,1024]
  const float* b_out      = (const float*)d_in[8];   // [1024]
  const int*   enc_len    = (const int*)  d_in[9];   // [32]

  float* out_ctx  = (float*)d_out;                   // [32,1024]
  float* out_attn = (float*)d_out + BATCH * DIM;     // [32,2048]

  // workspace layout:
  //   Wt    @ 0        : 2 MB   (bf16 W_enc^T)
  //   score @ 2 MB     : 256 KB (zeroed)
  //   ctx   @ 2.25 MB  : 128 KB (zeroed)
  //   dech  @ 2.375 MB : 128 KB (zeroed)
  //   Abf   @ 3 MB     : 128 MB (bf16 enc_states) -- fast path only
  char* ws = (char*)d_ws;
  unsigned short* Wt  = (unsigned short*)ws;
  float* score = (float*)(ws + (2u << 20));
  float* ctx   = (float*)(ws + (2u << 20) + 262144);
  float* dech  = (float*)(ws + (2u << 20) + 262144 + 131072);
  unsigned short* Abf = (unsigned short*)(ws + (3u << 20));
  const bool fast = ws_size >= ((size_t)(3u << 20) + ((size_t)MROWS * DIM * 2));

  // zero score + ctx + dech (all atomically accumulated)
  hipMemsetAsync(ws + (2u << 20), 0, 262144 + 131072 + 131072, stream);
  // zero out_ctx (atomically accumulated by k_out)
  hipMemsetAsync(d_out, 0, (size_t)BATCH * DIM * sizeof(float), stream);

  k_transpose<<<dim3(32, 32), dim3(32, 8), 0, stream>>>(W_enc, Wt);
  k_dech<<<dim3(4, BATCH, 8), 256, 0, stream>>>(dec_states, W_dec, b_dec, b_enc, dech);
  if (fast) {
    k_convert<<<dim3(SEQ / 8, BATCH), 256, 0, stream>>>(enc_states, enc_len, Abf);
    k_gemm256<<<1024, 512, 0, stream>>>(Abf, Wt, dech, w_attn, enc_len, score);
  } else {
    k_gemm_f32<<<4096, 256, 0, stream>>>(enc_states, Wt, dech, w_attn, enc_len, score);
  }
  k_softmax<<<BATCH, 256, 0, stream>>>(score, enc_len, out_attn);
  k_context<<<dim3(64, BATCH), 256, 0, stream>>>(enc_states, out_attn, enc_len, ctx);
  k_out<<<dim3(4, BATCH, 8), 256, 0, stream>>>(ctx, W_out, b_out, out_ctx);
}